// Round 1
// baseline (256.827 us; speedup 1.0000x reference)
//
#include <hip/hip_runtime.h>

// LocallyConnected1d: out[b,o,l] = sum_i sum_k x[b,i,l+k-4] * w[i,o,k,l] + bias[o,l]
// x:      [64][64][512]   fp32
// weight: [64][64][9][512] fp32  (i, o, k, l)  -- l innermost => coalesce along l
// bias:   [64][512]
// out:    [64][64][512]
//
// Thread tile: 4 batches x 1 o x 4 consecutive l (one float4 quad).
// PAD=4 == quad size, so halo handling is whole-quad zeroing (lq==0 / lq==127).
// Block: 256 thr = 64 l-lanes x 4 b-groups. Grid (2 l-halves, 64 o, 4 b-tiles)
// = 512 blocks = 2 blocks/CU. Weight float4 loads are identical across the 4
// waves of a block -> L1 broadcast; b-tile blocks are blockIdx stride 128
// apart -> same XCD -> weight L2 slice shared, ~read-once from HBM.

#define CIN   64
#define COUT  64
#define SEQ   512
#define KS    9
#define BATCH 64

__global__ __launch_bounds__(256, 2)
void lc1d_kernel(const float* __restrict__ x,
                 const float* __restrict__ w,
                 const float* __restrict__ bias,
                 float* __restrict__ out)
{
    const int lane = threadIdx.x & 63;
    const int bgrp = threadIdx.x >> 6;            // 0..3
    const int lq   = blockIdx.x * 64 + lane;      // 0..127 (quad index, l0 = 4*lq)
    const int l0   = lq * 4;
    const int o    = blockIdx.y;
    const int b0   = blockIdx.z * 16 + bgrp * 4;  // 4 batches per thread

    float acc[4][4];
    #pragma unroll
    for (int b = 0; b < 4; ++b)
        #pragma unroll
        for (int j = 0; j < 4; ++j) acc[b][j] = 0.f;

    const bool left_edge  = (lq == 0);    // needs x[-4..-1]   -> zeros (pad)
    const bool right_edge = (lq == 127);  // needs x[512..515] -> zeros (pad)

    for (int i = 0; i < CIN; ++i) {
        // 9 weight quads w[i,o,k,l0..l0+3], coalesced across lanes.
        float4 wv[KS];
        const float* wp = w + ((size_t)(i * COUT + o) * KS) * SEQ + l0;
        #pragma unroll
        for (int k = 0; k < KS; ++k)
            wv[k] = *(const float4*)(wp + k * SEQ);

        #pragma unroll
        for (int b = 0; b < 4; ++b) {
            const float* xp = x + ((size_t)((b0 + b) * CIN + i)) * SEQ + l0;
            float4 xa = left_edge  ? make_float4(0.f,0.f,0.f,0.f)
                                   : *(const float4*)(xp - 4);
            float4 xb = *(const float4*)(xp);
            float4 xc = right_edge ? make_float4(0.f,0.f,0.f,0.f)
                                   : *(const float4*)(xp + 4);
            // xwin[m] = x[b, i, l0 - 4 + m], m = 0..11
            float xwin[12] = {xa.x,xa.y,xa.z,xa.w,
                              xb.x,xb.y,xb.z,xb.w,
                              xc.x,xc.y,xc.z,xc.w};
            #pragma unroll
            for (int k = 0; k < KS; ++k) {
                const float4 wk = wv[k];
                // out l = l0+j needs x[l0+j+k-4] = xwin[j+k]
                acc[b][0] = fmaf(wk.x, xwin[0 + k], acc[b][0]);
                acc[b][1] = fmaf(wk.y, xwin[1 + k], acc[b][1]);
                acc[b][2] = fmaf(wk.z, xwin[2 + k], acc[b][2]);
                acc[b][3] = fmaf(wk.w, xwin[3 + k], acc[b][3]);
            }
        }
    }

    const float4 bv = *(const float4*)(bias + o * SEQ + l0);
    #pragma unroll
    for (int b = 0; b < 4; ++b) {
        float4 r;
        r.x = acc[b][0] + bv.x;
        r.y = acc[b][1] + bv.y;
        r.z = acc[b][2] + bv.z;
        r.w = acc[b][3] + bv.w;
        *(float4*)(out + ((size_t)((b0 + b) * COUT + o)) * SEQ + l0) = r;
    }
}

extern "C" void kernel_launch(void* const* d_in, const int* in_sizes, int n_in,
                              void* d_out, int out_size, void* d_ws, size_t ws_size,
                              hipStream_t stream) {
    const float* x    = (const float*)d_in[0];
    const float* wgt  = (const float*)d_in[1];
    const float* bias = (const float*)d_in[2];
    float* out        = (float*)d_out;

    dim3 grid(2, COUT, BATCH / 16);  // (l halves, o, b-tiles of 16)
    dim3 block(256);
    lc1d_kernel<<<grid, block, 0, stream>>>(x, wgt, bias, out);
}